// Round 12
// baseline (2611.372 us; speedup 1.0000x reference)
//
#include <hip/hip_runtime.h>
#include <hip/hip_fp16.h>
#include <cstddef>
#include <cstdint>

#define U_DIM 256
#define G_DIM 1024          // 4*U
#define T_DIM 512
#define B_DIM 64
#define TC    32            // timesteps per chunk
#define NCHUNK (T_DIM / TC) // 16
#define NPART  8            // final-proj j-range parts

// Weight residency split (proven round-9 structure)
#define NG_TOT 32
#define NG_REG 23
#define NG_LDS 9

typedef _Float16 half2v __attribute__((ext_vector_type(2)));
typedef _Float16 f16x8  __attribute__((ext_vector_type(8)));
typedef float    f32x4  __attribute__((ext_vector_type(4)));

__device__ __forceinline__ float fsig(float x) {
    return 1.0f / (1.0f + __expf(-x));
}
__device__ __forceinline__ float ftanh(float x) {
    return 2.0f * fsig(2.0f * x) - 1.0f;
}

#define PIN4(v) asm("" : "+v"(v.x), "+v"(v.y), "+v"(v.z), "+v"(v.w))

// ---------------------------------------------------------------------------
// Pack U [256,1024] fp32 -> P: [32 groups][1024 cols] of uint4.
// P[g][n] holds f16(U[8g+0..8g+7][n]) packed 2-per-u32.
// (Also the MFMA B-fragment layout, verified rounds 7/10/11.)
// ---------------------------------------------------------------------------
__global__ __launch_bounds__(256)
void pack_w(const float* __restrict__ U, uint4* __restrict__ P)
{
    const int idx = blockIdx.x * 256 + threadIdx.x;   // 0..32767
    const int g = idx >> 10;
    const int n = idx & 1023;
    uint vals[4];
    #pragma unroll
    for (int j = 0; j < 4; ++j) {
        const int k = g * 8 + j * 2;
        const __half a = __float2half_rn(U[(size_t)k * G_DIM + n]);
        const __half b = __float2half_rn(U[(size_t)(k + 1) * G_DIM + n]);
        const unsigned short ua = __builtin_bit_cast(unsigned short, a);
        const unsigned short ub = __builtin_bit_cast(unsigned short, b);
        vals[j] = (uint)ua | ((uint)ub << 16);
    }
    P[idx] = make_uint4(vals[0], vals[1], vals[2], vals[3]);
}

// Pack x f32 -> f16, 8 elems/thread.
__global__ __launch_bounds__(256)
void pack_x(const float* __restrict__ x, __half* __restrict__ xh)
{
    const size_t i = ((size_t)blockIdx.x * 256 + threadIdx.x) * 8;
    const float4 a = *(const float4*)(x + i);
    const float4 b = *(const float4*)(x + i + 4);
    ushort4 o0, o1;
    o0.x = __builtin_bit_cast(unsigned short, __float2half_rn(a.x));
    o0.y = __builtin_bit_cast(unsigned short, __float2half_rn(a.y));
    o0.z = __builtin_bit_cast(unsigned short, __float2half_rn(a.z));
    o0.w = __builtin_bit_cast(unsigned short, __float2half_rn(a.w));
    o1.x = __builtin_bit_cast(unsigned short, __float2half_rn(b.x));
    o1.y = __builtin_bit_cast(unsigned short, __float2half_rn(b.y));
    o1.z = __builtin_bit_cast(unsigned short, __float2half_rn(b.z));
    o1.w = __builtin_bit_cast(unsigned short, __float2half_rn(b.w));
    *(ushort4*)(xh + i) = o0;
    *(ushort4*)(xh + i + 4) = o1;
}

// 8 MACs: acc += sum_j f16(h)[j] * f16(w)[j]
__device__ __forceinline__ float mac8(float acc, uint4 w, uint4 h)
{
#if __has_builtin(__builtin_amdgcn_fdot2)
    acc = __builtin_amdgcn_fdot2(__builtin_bit_cast(half2v, h.x),
                                 __builtin_bit_cast(half2v, w.x), acc, false);
    acc = __builtin_amdgcn_fdot2(__builtin_bit_cast(half2v, h.y),
                                 __builtin_bit_cast(half2v, w.y), acc, false);
    acc = __builtin_amdgcn_fdot2(__builtin_bit_cast(half2v, h.z),
                                 __builtin_bit_cast(half2v, w.z), acc, false);
    acc = __builtin_amdgcn_fdot2(__builtin_bit_cast(half2v, h.w),
                                 __builtin_bit_cast(half2v, w.w), acc, false);
#else
    const uint wv[4] = {w.x, w.y, w.z, w.w};
    const uint hv[4] = {h.x, h.y, h.z, h.w};
    #pragma unroll
    for (int j = 0; j < 4; ++j) {
        const __half2 wp = __builtin_bit_cast(__half2, wv[j]);
        const __half2 hp = __builtin_bit_cast(__half2, hv[j]);
        acc += __half2float(hp.x) * __half2float(wp.x);
        acc += __half2float(hp.y) * __half2float(wp.y);
    }
#endif
    return acc;
}

// ---------------------------------------------------------------------------
// PERSISTENT pipelined LSTM. Cooperative grid = 192 blocks x 512 threads,
// 1 block/CU (147 KB LDS). Block = (layer = bid>>6, row b = bid&63).
// Per chunk: wait device-scope flag -> inline MFMA xz -> 32 recurrent steps
// (round-9 structure, unchanged) -> release-publish flag.
// Weights preload ONCE per launch (was 18x).
// ---------------------------------------------------------------------------
__global__
__attribute__((amdgpu_flat_work_group_size(512, 512)))
__attribute__((amdgpu_waves_per_eu(2, 2)))
void lstm_persist(const __half* __restrict__ xh,
                  const uint4* __restrict__ Pr, const uint4* __restrict__ Pn,
                  const uint4* __restrict__ PWr, const uint4* __restrict__ PWn,
                  const float* __restrict__ br, const float* __restrict__ bn,
                  __half* __restrict__ h0, __half* __restrict__ h1,
                  __half* __restrict__ xzAll, float* __restrict__ hs2,
                  unsigned* __restrict__ flags)
{
    const int layer = blockIdx.x >> 6;
    const int b     = blockIdx.x & 63;
    const int t = threadIdx.x;      // 0..511
    const int w = t >> 6;           // wave id (gemm phase)
    const int l = t & 63;
    const int krow = l >> 4;
    const int n0 = t;               // step phase: column A
    const int n1 = t + 512;         // step phase: column B

    const uint4* __restrict__ P    = (layer < 2) ? Pr : Pn;
    const uint4* __restrict__ PW   = (layer < 2) ? PWr : PWn;
    const float* __restrict__ bias = (layer < 2) ? br : bn;
    const __half* __restrict__ src =
        ((layer == 0) ? xh : (layer == 1) ? h0 : h1) + (size_t)b * T_DIM * U_DIM;
    __half* __restrict__ outseq =
        (layer == 0) ? (h0 + (size_t)b * T_DIM * U_DIM)
      : (layer == 1) ? (h1 + (size_t)b * T_DIM * U_DIM) : nullptr;
    const __half* __restrict__ resbase =
        (layer == 1) ? (h0 + (size_t)b * T_DIM * U_DIM) : nullptr;
    __half* __restrict__ xzb = xzAll + (size_t)(layer * B_DIM + b) * (TC * G_DIM);
    unsigned* __restrict__ wflag = (layer > 0) ? (flags + (layer - 1) * B_DIM + b) : nullptr;
    unsigned* __restrict__ pflag = (layer < 2) ? (flags + layer * B_DIM + b) : nullptr;

    __shared__ __align__(16) uint hq[U_DIM / 2];   // h packed f16 (512 B)
    __shared__ float csh[U_DIM];
    __shared__ float zsh[G_DIM];
    __shared__ uint4 wlds[NG_LDS][G_DIM];          // 147 KB

    // ---- one-time recurrent weight preload ----
    uint4 wA[NG_REG], wB[NG_REG];
    #pragma unroll
    for (int g = 0; g < NG_REG; ++g) {
        wA[g] = P[(size_t)g * G_DIM + n0];
        wB[g] = P[(size_t)g * G_DIM + n1];
    }
    #pragma unroll
    for (int g = 0; g < NG_REG; ++g) { PIN4(wA[g]); PIN4(wB[g]); }
    #pragma unroll
    for (int g = 0; g < NG_LDS; ++g) {
        wlds[g][n0] = P[(size_t)(NG_REG + g) * G_DIM + n0];
        wlds[g][n1] = P[(size_t)(NG_REG + g) * G_DIM + n1];
    }

    if (t < U_DIM) { csh[t] = 0.0f; ((__half*)hq)[t] = __float2half_rn(0.0f); }
    __syncthreads();

    for (int c = 0; c < NCHUNK; ++c) {
        const int t0 = c * TC;

        // ---- wait for producer's chunk c ----
        if (wflag) {
            if (t == 0) {
                while (__hip_atomic_load(wflag, __ATOMIC_ACQUIRE,
                                         __HIP_MEMORY_SCOPE_AGENT) < (unsigned)(c + 1))
                    __builtin_amdgcn_s_sleep(2);
            }
            __syncthreads();
        }

        // ---- inline xz GEMM: xzb[0..TC-1][:] = src[t0..t0+TC-1,:] @ W + bias
        // Fragment layouts verified rounds 7/10/11. Wave w: cols w*128..+127.
        #pragma unroll
        for (int ct = 0; ct < 8; ++ct) {
            const int col = w * 128 + ct * 16 + (l & 15);
            f32x4 acc0 = {0.f, 0.f, 0.f, 0.f};
            f32x4 acc1 = {0.f, 0.f, 0.f, 0.f};
            const __half* a0p = src + (size_t)(t0 + (l & 15)) * U_DIM + krow * 8;
            const __half* a1p = a0p + 16 * U_DIM;
            #pragma unroll
            for (int kt = 0; kt < 8; ++kt) {
                const uint4 bfrag = PW[(size_t)(4 * kt + krow) * G_DIM + col];
                const uint4 a0 = *(const uint4*)(a0p + kt * 32);
                const uint4 a1 = *(const uint4*)(a1p + kt * 32);
                acc0 = __builtin_amdgcn_mfma_f32_16x16x32_f16(
                    __builtin_bit_cast(f16x8, a0), __builtin_bit_cast(f16x8, bfrag),
                    acc0, 0, 0, 0);
                acc1 = __builtin_amdgcn_mfma_f32_16x16x32_f16(
                    __builtin_bit_cast(f16x8, a1), __builtin_bit_cast(f16x8, bfrag),
                    acc1, 0, 0, 0);
            }
            const float bv = bias[col];
            #pragma unroll
            for (int r = 0; r < 4; ++r) {
                const int row0 = 4 * krow + r;
                xzb[(size_t)row0 * G_DIM + col]        = __float2half_rn(acc0[r] + bv);
                xzb[(size_t)(row0 + 16) * G_DIM + col] = __float2half_rn(acc1[r] + bv);
            }
        }
        __syncthreads();   // drains vmcnt: xz visible to all waves of this block

        // ---- 32 recurrent steps (round-9 structure) ----
        const __half* __restrict__ resb = resbase ? (resbase + (size_t)t0 * U_DIM) : nullptr;
        __half* __restrict__ outb = outseq ? (outseq + (size_t)t0 * U_DIM) : nullptr;

        float cur0 = __half2float(xzb[n0]);
        float cur1 = __half2float(xzb[n1]);
        float resv = (resb && t < U_DIM) ? __half2float(resb[t]) : 0.0f;

        for (int tl = 0; tl < TC; ++tl) {
            float acc0 = cur0;
            float acc1 = cur1;

            const int tn = (tl + 1 < TC) ? (tl + 1) : (TC - 1);
            cur0 = __half2float(xzb[(size_t)tn * G_DIM + n0]);
            cur1 = __half2float(xzb[(size_t)tn * G_DIM + n1]);
            const float resn = (resb && t < U_DIM)
                             ? __half2float(resb[(size_t)tn * U_DIM + t]) : 0.0f;

            const uint4* __restrict__ hp = (const uint4*)hq;

            #pragma unroll
            for (int g = 0; g < NG_REG; ++g) {
                const uint4 h4 = hp[g];
                acc0 = mac8(acc0, wA[g], h4);
                acc1 = mac8(acc1, wB[g], h4);
            }
            #pragma unroll
            for (int g = 0; g < NG_LDS; ++g) {
                const uint4 h4 = hp[NG_REG + g];
                acc0 = mac8(acc0, wlds[g][n0], h4);
                acc1 = mac8(acc1, wlds[g][n1], h4);
            }

            zsh[n0] = fsig(acc0);
            zsh[n1] = (t < U_DIM) ? ftanh(acc1) : fsig(acc1);
            __syncthreads();

            if (t < U_DIM) {
                const float iv = zsh[t];
                const float fv = zsh[t + 256];
                const float gv = zsh[t + 512];
                const float ov = zsh[t + 768];
                const float cc = fv * csh[t] + iv * gv;
                const float hh = ov * ftanh(cc);
                csh[t] = cc;
                ((__half*)hq)[t] = __float2half_rn(hh);
                if (outb) outb[(size_t)tl * U_DIM + t] = __float2half_rn(hh + resv);
            }
            resv = resn;
            __syncthreads();
        }

        // ---- publish chunk c (prior global writes drained by step syncthreads) ----
        if (pflag && t == 0)
            __hip_atomic_store(pflag, (unsigned)(c + 1), __ATOMIC_RELEASE,
                               __HIP_MEMORY_SCOPE_AGENT);
    }

    if (layer == 2 && t < U_DIM)
        hs2[b * U_DIM + t] = __half2float(((const __half*)hq)[t]);
}

// ---------------------------------------------------------------------------
// Final projection, stage A + B (unchanged).
// ---------------------------------------------------------------------------
__global__ __launch_bounds__(256)
void final_partial(const __half* __restrict__ h1, const float* __restrict__ h2,
                   const float* __restrict__ Wd, float* __restrict__ partials)
{
    const int b = blockIdx.x;
    const int p = blockIdx.y;
    const int tid = threadIdx.x;
    const int JTOT = T_DIM * U_DIM;          // 131072
    const int JPART = JTOT / NPART;          // 16384

    const __half* hb = h1 + (size_t)b * JTOT;
    const float* h2b = h2 + (size_t)b * U_DIM;

    float a0 = 0.f, a1 = 0.f, a2 = 0.f, a3 = 0.f;

    for (int j = p * JPART + tid * 8; j < (p + 1) * JPART; j += 256 * 8) {
        const uint4 hv = *(const uint4*)(hb + j);
        const int m = j & (U_DIM - 1);
        const float4 s0 = *(const float4*)(h2b + m);
        const float4 s1 = *(const float4*)(h2b + m + 4);
        float v[8];
        {
            const __half2 p0 = __builtin_bit_cast(__half2, hv.x);
            const __half2 p1 = __builtin_bit_cast(__half2, hv.y);
            const __half2 p2 = __builtin_bit_cast(__half2, hv.z);
            const __half2 p3 = __builtin_bit_cast(__half2, hv.w);
            v[0] = __half2float(p0.x) + s0.x;
            v[1] = __half2float(p0.y) + s0.y;
            v[2] = __half2float(p1.x) + s0.z;
            v[3] = __half2float(p1.y) + s0.w;
            v[4] = __half2float(p2.x) + s1.x;
            v[5] = __half2float(p2.y) + s1.y;
            v[6] = __half2float(p3.x) + s1.z;
            v[7] = __half2float(p3.y) + s1.w;
        }
        #pragma unroll
        for (int u = 0; u < 8; ++u) {
            const float4 wv = *(const float4*)&Wd[(size_t)(j + u) * 4];
            a0 += v[u] * wv.x;
            a1 += v[u] * wv.y;
            a2 += v[u] * wv.z;
            a3 += v[u] * wv.w;
        }
    }

    __shared__ float red[256][4];
    red[tid][0] = a0; red[tid][1] = a1; red[tid][2] = a2; red[tid][3] = a3;
    __syncthreads();
    for (int s = 128; s > 0; s >>= 1) {
        if (tid < s) {
            #pragma unroll
            for (int o = 0; o < 4; ++o) red[tid][o] += red[tid + s][o];
        }
        __syncthreads();
    }
    if (tid < 4) partials[((size_t)b * NPART + p) * 4 + tid] = red[0][tid];
}

__global__ __launch_bounds__(256)
void final_reduce(const float* __restrict__ partials, const float* __restrict__ bd,
                  float* __restrict__ y)
{
    const int tid = threadIdx.x;
    const int b = tid >> 2;
    const int o = tid & 3;
    float s = bd[o];
    #pragma unroll
    for (int p = 0; p < NPART; ++p)
        s += partials[((size_t)b * NPART + p) * 4 + o];
    y[b * 4 + o] = s;
}

// ---------------------------------------------------------------------------
extern "C" void kernel_launch(void* const* d_in, const int* in_sizes, int n_in,
                              void* d_out, int out_size, void* d_ws, size_t ws_size,
                              hipStream_t stream)
{
    (void)in_sizes; (void)n_in; (void)out_size; (void)ws_size;

    const float* x  = (const float*)d_in[0];
    const float* Wr = (const float*)d_in[1];
    const float* Ur = (const float*)d_in[2];
    const float* br = (const float*)d_in[3];
    const float* Wn = (const float*)d_in[4];
    const float* Un = (const float*)d_in[5];
    const float* bn = (const float*)d_in[6];
    const float* Wd = (const float*)d_in[7];
    const float* bd = (const float*)d_in[8];
    float* y = (float*)d_out;

    // ---- workspace layout ----
    char* wp = (char*)d_ws;
    uint4* Pr  = (uint4*)wp;  wp += (size_t)NG_TOT * G_DIM * 16;   // 512 KB
    uint4* Pn  = (uint4*)wp;  wp += (size_t)NG_TOT * G_DIM * 16;   // 512 KB
    uint4* PWr = (uint4*)wp;  wp += (size_t)NG_TOT * G_DIM * 16;   // 512 KB
    uint4* PWn = (uint4*)wp;  wp += (size_t)NG_TOT * G_DIM * 16;   // 512 KB
    float* hs2 = (float*)wp;  wp += (size_t)B_DIM * U_DIM * 4;     // 64 KB
    float* partials = (float*)wp;   wp += (size_t)B_DIM * NPART * 4 * 4;   // 8 KB
    unsigned* flags = (unsigned*)wp; wp += 2 * B_DIM * sizeof(unsigned);   // 512 B
    wp = (char*)(((uintptr_t)wp + 255) & ~(uintptr_t)255);
    __half* xzAll = (__half*)wp; wp += (size_t)3 * B_DIM * TC * G_DIM * 2; // 12.6 MB
    __half* h0 = (__half*)wp;    wp += (size_t)B_DIM * T_DIM * U_DIM * 2;  // 16.8 MB
    __half* h1 = (__half*)wp;    wp += (size_t)B_DIM * T_DIM * U_DIM * 2;  // 16.8 MB
    __half* xh = (__half*)wp;    wp += (size_t)B_DIM * T_DIM * U_DIM * 2;  // 16.8 MB
    // total ~66 MB

    // ---- one-time packs ----
    pack_w<<<128, 256, 0, stream>>>(Ur, Pr);
    pack_w<<<128, 256, 0, stream>>>(Un, Pn);
    pack_w<<<128, 256, 0, stream>>>(Wr, PWr);
    pack_w<<<128, 256, 0, stream>>>(Wn, PWn);
    pack_x<<<(B_DIM * T_DIM * U_DIM) / (256 * 8), 256, 0, stream>>>(x, xh);

    // ---- reset flags, one persistent cooperative dispatch ----
    hipMemsetAsync(flags, 0, 2 * B_DIM * sizeof(unsigned), stream);

    const __half* xh_c = xh;
    const uint4 *Pr_c = Pr, *Pn_c = Pn, *PWr_c = PWr, *PWn_c = PWn;
    const float *br_c = br, *bn_c = bn;
    void* kargs[] = {
        (void*)&xh_c, (void*)&Pr_c, (void*)&Pn_c, (void*)&PWr_c, (void*)&PWn_c,
        (void*)&br_c, (void*)&bn_c, (void*)&h0, (void*)&h1,
        (void*)&xzAll, (void*)&hs2, (void*)&flags
    };
    hipLaunchCooperativeKernel((void*)lstm_persist, dim3(3 * B_DIM), dim3(512),
                               kargs, 0, stream);

    // ---- final projection ----
    final_partial<<<dim3(B_DIM, NPART), 256, 0, stream>>>(h1, hs2, Wd, partials);
    final_reduce<<<1, 256, 0, stream>>>(partials, bd, y);
}

// Round 13
// 2016.789 us; speedup vs baseline: 1.2948x; 1.2948x over previous
//
#include <hip/hip_runtime.h>
#include <hip/hip_fp16.h>
#include <cstddef>
#include <cstdint>

#define U_DIM 256
#define G_DIM 1024          // 4*U
#define T_DIM 512
#define B_DIM 64
#define TC    32            // timesteps per chunk
#define NCHUNK (T_DIM / TC) // 16
#define NSLOT  (NCHUNK + 2) // 18 pipeline slots
#define BHID   (B_DIM * U_DIM)
#define NPART  8            // final-proj j-range parts

// Weight residency split (proven round-9/11 structure)
#define NG_TOT 32
#define NG_REG 23
#define NG_LDS 9

#if __has_builtin(__builtin_amdgcn_global_load_lds)
#define HAS_GLL 1
#else
#define HAS_GLL 0
#endif

typedef _Float16 half2v __attribute__((ext_vector_type(2)));
typedef _Float16 f16x8  __attribute__((ext_vector_type(8)));
typedef float    f32x4  __attribute__((ext_vector_type(4)));

__device__ __forceinline__ float fsig(float x) {
    return 1.0f / (1.0f + __expf(-x));
}
__device__ __forceinline__ float ftanh(float x) {
    return 2.0f * fsig(2.0f * x) - 1.0f;
}

#define PIN4(v) asm("" : "+v"(v.x), "+v"(v.y), "+v"(v.z), "+v"(v.w))

// ---------------------------------------------------------------------------
// Pack U [256,1024] fp32 -> P: [32 groups][1024 cols] of uint4.
// P[g][n] holds f16(U[8g+0..8g+7][n]) packed 2-per-u32.
// (Also the MFMA B-fragment layout, verified rounds 7/10/11/12.)
// ---------------------------------------------------------------------------
__global__ __launch_bounds__(256)
void pack_w(const float* __restrict__ U, uint4* __restrict__ P)
{
    const int idx = blockIdx.x * 256 + threadIdx.x;   // 0..32767
    const int g = idx >> 10;
    const int n = idx & 1023;
    uint vals[4];
    #pragma unroll
    for (int j = 0; j < 4; ++j) {
        const int k = g * 8 + j * 2;
        const __half a = __float2half_rn(U[(size_t)k * G_DIM + n]);
        const __half b = __float2half_rn(U[(size_t)(k + 1) * G_DIM + n]);
        const unsigned short ua = __builtin_bit_cast(unsigned short, a);
        const unsigned short ub = __builtin_bit_cast(unsigned short, b);
        vals[j] = (uint)ua | ((uint)ub << 16);
    }
    P[idx] = make_uint4(vals[0], vals[1], vals[2], vals[3]);
}

// Pack x f32 -> f16, 8 elems/thread.
__global__ __launch_bounds__(256)
void pack_x(const float* __restrict__ x, __half* __restrict__ xh)
{
    const size_t i = ((size_t)blockIdx.x * 256 + threadIdx.x) * 8;
    const float4 a = *(const float4*)(x + i);
    const float4 b = *(const float4*)(x + i + 4);
    ushort4 o0, o1;
    o0.x = __builtin_bit_cast(unsigned short, __float2half_rn(a.x));
    o0.y = __builtin_bit_cast(unsigned short, __float2half_rn(a.y));
    o0.z = __builtin_bit_cast(unsigned short, __float2half_rn(a.z));
    o0.w = __builtin_bit_cast(unsigned short, __float2half_rn(a.w));
    o1.x = __builtin_bit_cast(unsigned short, __float2half_rn(b.x));
    o1.y = __builtin_bit_cast(unsigned short, __float2half_rn(b.y));
    o1.z = __builtin_bit_cast(unsigned short, __float2half_rn(b.z));
    o1.w = __builtin_bit_cast(unsigned short, __float2half_rn(b.w));
    *(ushort4*)(xh + i) = o0;
    *(ushort4*)(xh + i + 4) = o1;
}

// 8 MACs: acc += sum_j f16(h)[j] * f16(w)[j]
__device__ __forceinline__ float mac8(float acc, uint4 w, uint4 h)
{
#if __has_builtin(__builtin_amdgcn_fdot2)
    acc = __builtin_amdgcn_fdot2(__builtin_bit_cast(half2v, h.x),
                                 __builtin_bit_cast(half2v, w.x), acc, false);
    acc = __builtin_amdgcn_fdot2(__builtin_bit_cast(half2v, h.y),
                                 __builtin_bit_cast(half2v, w.y), acc, false);
    acc = __builtin_amdgcn_fdot2(__builtin_bit_cast(half2v, h.z),
                                 __builtin_bit_cast(half2v, w.z), acc, false);
    acc = __builtin_amdgcn_fdot2(__builtin_bit_cast(half2v, h.w),
                                 __builtin_bit_cast(half2v, w.w), acc, false);
#else
    const uint wv[4] = {w.x, w.y, w.z, w.w};
    const uint hv[4] = {h.x, h.y, h.z, h.w};
    #pragma unroll
    for (int j = 0; j < 4; ++j) {
        const __half2 wp = __builtin_bit_cast(__half2, wv[j]);
        const __half2 hp = __builtin_bit_cast(__half2, hv[j]);
        acc += __half2float(hp.x) * __half2float(wp.x);
        acc += __half2float(hp.y) * __half2float(wp.y);
    }
#endif
    return acc;
}

// ---------------------------------------------------------------------------
// FUSED per-slot kernel: grid = 192 blocks (3 layers x 64 rows) x 512 threads.
// Block (layer, b) at slot computes chunk c = slot - layer (skip if invalid):
//   phase A: async wlds preload (global_load_lds) + wreg preload
//   phase B: inline MFMA xz GEMM  (round-12 code, correctness-proven)
//   phase C: 32 recurrent steps   (round-9 structure, 1.96 us/step floor)
// NO atomics/flags: all cross-layer reads are >=1 dispatch old (stream order).
// ---------------------------------------------------------------------------
__global__
__attribute__((amdgpu_flat_work_group_size(512, 512)))
__attribute__((amdgpu_waves_per_eu(2, 2)))
void lstm_slot(int slot,
               const __half* __restrict__ xh,
               const uint4* __restrict__ Pr, const uint4* __restrict__ Pn,
               const uint4* __restrict__ PWr, const uint4* __restrict__ PWn,
               const float* __restrict__ br, const float* __restrict__ bn,
               __half* __restrict__ h0, __half* __restrict__ h1,
               __half* __restrict__ xzAll,
               float* __restrict__ hsAll, float* __restrict__ csAll)
{
    const int layer = blockIdx.x >> 6;
    const int b     = blockIdx.x & 63;
    const int c     = slot - layer;
    if ((unsigned)c >= (unsigned)NCHUNK) return;
    const int t0 = c * TC;

    const int t = threadIdx.x;      // 0..511
    const int w = t >> 6;           // wave id (gemm phase)
    const int l = t & 63;
    const int krow = l >> 4;
    const int n0 = t;               // step phase: column A
    const int n1 = t + 512;         // step phase: column B

    const uint4* __restrict__ P    = (layer < 2) ? Pr : Pn;
    const uint4* __restrict__ PW   = (layer < 2) ? PWr : PWn;
    const float* __restrict__ bias = (layer < 2) ? br : bn;
    const __half* __restrict__ src =
        ((layer == 0) ? xh : (layer == 1) ? h0 : h1) + (size_t)b * T_DIM * U_DIM;
    __half* __restrict__ outseq =
        (layer == 0) ? (h0 + (size_t)b * T_DIM * U_DIM)
      : (layer == 1) ? (h1 + (size_t)b * T_DIM * U_DIM) : nullptr;
    const __half* __restrict__ resbase =
        (layer == 1) ? (h0 + (size_t)b * T_DIM * U_DIM) : nullptr;
    __half* __restrict__ xzb = xzAll + (size_t)(layer * B_DIM + b) * (TC * G_DIM);
    float* __restrict__ hstate = hsAll + (size_t)layer * BHID + b * U_DIM;
    float* __restrict__ cstate = csAll + (size_t)layer * BHID + b * U_DIM;

    __shared__ __align__(16) uint hq[U_DIM / 2];   // h packed f16 (512 B)
    __shared__ float csh[U_DIM];
    __shared__ float zsh[G_DIM];
    __shared__ uint4 wlds[NG_LDS][G_DIM];          // 147 KB

    // ---- phase A: async wlds preload (drained by the barrier after gemm) ----
#if HAS_GLL
    #pragma unroll
    for (int g = 0; g < NG_LDS; ++g) {
        #pragma unroll
        for (int s = 0; s < 2; ++s) {
            const int cb = s * 512 + w * 64;   // wave-uniform slice base
            __builtin_amdgcn_global_load_lds(
                (const __attribute__((address_space(1))) void*)
                    (P + (size_t)(NG_REG + g) * G_DIM + cb + l),
                (__attribute__((address_space(3))) void*)&wlds[g][cb],
                16, 0, 0);
        }
    }
#else
    #pragma unroll
    for (int g = 0; g < NG_LDS; ++g) {
        wlds[g][n0] = P[(size_t)(NG_REG + g) * G_DIM + n0];
        wlds[g][n1] = P[(size_t)(NG_REG + g) * G_DIM + n1];
    }
#endif

    // wreg preload (consumed in phase C; compiler may overlap with phase B)
    uint4 wA[NG_REG], wB[NG_REG];
    #pragma unroll
    for (int g = 0; g < NG_REG; ++g) {
        wA[g] = P[(size_t)g * G_DIM + n0];
        wB[g] = P[(size_t)g * G_DIM + n1];
    }
    #pragma unroll
    for (int g = 0; g < NG_REG; ++g) { PIN4(wA[g]); PIN4(wB[g]); }

    // carry state -> LDS / reg
    if (t < U_DIM) {
        float hv, cv;
        if (c == 0) { hv = 0.0f; cv = 0.0f; }
        else        { hv = hstate[t]; cv = cstate[t]; }
        csh[t] = cv;
        ((__half*)hq)[t] = __float2half_rn(hv);
    }

    // ---- phase B: inline MFMA xz GEMM (round-12 code, verified) ----
    #pragma unroll
    for (int ct = 0; ct < 8; ++ct) {
        const int col = w * 128 + ct * 16 + (l & 15);
        f32x4 acc0 = {0.f, 0.f, 0.f, 0.f};
        f32x4 acc1 = {0.f, 0.f, 0.f, 0.f};
        const __half* a0p = src + (size_t)(t0 + (l & 15)) * U_DIM + krow * 8;
        const __half* a1p = a0p + 16 * U_DIM;
        #pragma unroll
        for (int kt = 0; kt < 8; ++kt) {
            const uint4 bfrag = PW[(size_t)(4 * kt + krow) * G_DIM + col];
            const uint4 a0 = *(const uint4*)(a0p + kt * 32);
            const uint4 a1 = *(const uint4*)(a1p + kt * 32);
            acc0 = __builtin_amdgcn_mfma_f32_16x16x32_f16(
                __builtin_bit_cast(f16x8, a0), __builtin_bit_cast(f16x8, bfrag),
                acc0, 0, 0, 0);
            acc1 = __builtin_amdgcn_mfma_f32_16x16x32_f16(
                __builtin_bit_cast(f16x8, a1), __builtin_bit_cast(f16x8, bfrag),
                acc1, 0, 0, 0);
        }
        const float bv = bias[col];
        #pragma unroll
        for (int r = 0; r < 4; ++r) {
            const int row0 = 4 * krow + r;
            xzb[(size_t)row0 * G_DIM + col]        = __float2half_rn(acc0[r] + bv);
            xzb[(size_t)(row0 + 16) * G_DIM + col] = __float2half_rn(acc1[r] + bv);
        }
    }
    __syncthreads();   // drains vmcnt(0): wlds async loads + xz stores complete

    // ---- phase C: 32 recurrent steps (round-9 structure, unchanged) ----
    const __half* __restrict__ resb = resbase ? (resbase + (size_t)t0 * U_DIM) : nullptr;
    __half* __restrict__ outb = outseq ? (outseq + (size_t)t0 * U_DIM) : nullptr;

    float cur0 = __half2float(xzb[n0]);
    float cur1 = __half2float(xzb[n1]);
    float resv = (resb && t < U_DIM) ? __half2float(resb[t]) : 0.0f;

    for (int tl = 0; tl < TC; ++tl) {
        float acc0 = cur0;
        float acc1 = cur1;

        const int tn = (tl + 1 < TC) ? (tl + 1) : (TC - 1);
        cur0 = __half2float(xzb[(size_t)tn * G_DIM + n0]);
        cur1 = __half2float(xzb[(size_t)tn * G_DIM + n1]);
        const float resn = (resb && t < U_DIM)
                         ? __half2float(resb[(size_t)tn * U_DIM + t]) : 0.0f;

        const uint4* __restrict__ hp = (const uint4*)hq;

        #pragma unroll
        for (int g = 0; g < NG_REG; ++g) {
            const uint4 h4 = hp[g];
            acc0 = mac8(acc0, wA[g], h4);
            acc1 = mac8(acc1, wB[g], h4);
        }
        #pragma unroll
        for (int g = 0; g < NG_LDS; ++g) {
            const uint4 h4 = hp[NG_REG + g];
            acc0 = mac8(acc0, wlds[g][n0], h4);
            acc1 = mac8(acc1, wlds[g][n1], h4);
        }

        zsh[n0] = fsig(acc0);
        zsh[n1] = (t < U_DIM) ? ftanh(acc1) : fsig(acc1);
        __syncthreads();

        if (t < U_DIM) {
            const float iv = zsh[t];
            const float fv = zsh[t + 256];
            const float gv = zsh[t + 512];
            const float ov = zsh[t + 768];
            const float cc = fv * csh[t] + iv * gv;
            const float hh = ov * ftanh(cc);
            csh[t] = cc;
            ((__half*)hq)[t] = __float2half_rn(hh);
            if (outb) outb[(size_t)tl * U_DIM + t] = __float2half_rn(hh + resv);
        }
        resv = resn;
        __syncthreads();
    }

    if (t < U_DIM) {
        hstate[t] = __half2float(((const __half*)hq)[t]);
        cstate[t] = csh[t];
    }
}

// ---------------------------------------------------------------------------
// Final projection, stage A + B (unchanged).
// ---------------------------------------------------------------------------
__global__ __launch_bounds__(256)
void final_partial(const __half* __restrict__ h1, const float* __restrict__ h2,
                   const float* __restrict__ Wd, float* __restrict__ partials)
{
    const int b = blockIdx.x;
    const int p = blockIdx.y;
    const int tid = threadIdx.x;
    const int JTOT = T_DIM * U_DIM;          // 131072
    const int JPART = JTOT / NPART;          // 16384

    const __half* hb = h1 + (size_t)b * JTOT;
    const float* h2b = h2 + (size_t)b * U_DIM;

    float a0 = 0.f, a1 = 0.f, a2 = 0.f, a3 = 0.f;

    for (int j = p * JPART + tid * 8; j < (p + 1) * JPART; j += 256 * 8) {
        const uint4 hv = *(const uint4*)(hb + j);
        const int m = j & (U_DIM - 1);
        const float4 s0 = *(const float4*)(h2b + m);
        const float4 s1 = *(const float4*)(h2b + m + 4);
        float v[8];
        {
            const __half2 p0 = __builtin_bit_cast(__half2, hv.x);
            const __half2 p1 = __builtin_bit_cast(__half2, hv.y);
            const __half2 p2 = __builtin_bit_cast(__half2, hv.z);
            const __half2 p3 = __builtin_bit_cast(__half2, hv.w);
            v[0] = __half2float(p0.x) + s0.x;
            v[1] = __half2float(p0.y) + s0.y;
            v[2] = __half2float(p1.x) + s0.z;
            v[3] = __half2float(p1.y) + s0.w;
            v[4] = __half2float(p2.x) + s1.x;
            v[5] = __half2float(p2.y) + s1.y;
            v[6] = __half2float(p3.x) + s1.z;
            v[7] = __half2float(p3.y) + s1.w;
        }
        #pragma unroll
        for (int u = 0; u < 8; ++u) {
            const float4 wv = *(const float4*)&Wd[(size_t)(j + u) * 4];
            a0 += v[u] * wv.x;
            a1 += v[u] * wv.y;
            a2 += v[u] * wv.z;
            a3 += v[u] * wv.w;
        }
    }

    __shared__ float red[256][4];
    red[tid][0] = a0; red[tid][1] = a1; red[tid][2] = a2; red[tid][3] = a3;
    __syncthreads();
    for (int s = 128; s > 0; s >>= 1) {
        if (tid < s) {
            #pragma unroll
            for (int o = 0; o < 4; ++o) red[tid][o] += red[tid + s][o];
        }
        __syncthreads();
    }
    if (tid < 4) partials[((size_t)b * NPART + p) * 4 + tid] = red[0][tid];
}

__global__ __launch_bounds__(256)
void final_reduce(const float* __restrict__ partials, const float* __restrict__ bd,
                  float* __restrict__ y)
{
    const int tid = threadIdx.x;
    const int b = tid >> 2;
    const int o = tid & 3;
    float s = bd[o];
    #pragma unroll
    for (int p = 0; p < NPART; ++p)
        s += partials[((size_t)b * NPART + p) * 4 + o];
    y[b * 4 + o] = s;
}

// ---------------------------------------------------------------------------
extern "C" void kernel_launch(void* const* d_in, const int* in_sizes, int n_in,
                              void* d_out, int out_size, void* d_ws, size_t ws_size,
                              hipStream_t stream)
{
    (void)in_sizes; (void)n_in; (void)out_size; (void)ws_size;

    const float* x  = (const float*)d_in[0];
    const float* Wr = (const float*)d_in[1];
    const float* Ur = (const float*)d_in[2];
    const float* br = (const float*)d_in[3];
    const float* Wn = (const float*)d_in[4];
    const float* Un = (const float*)d_in[5];
    const float* bn = (const float*)d_in[6];
    const float* Wd = (const float*)d_in[7];
    const float* bd = (const float*)d_in[8];
    float* y = (float*)d_out;

    // ---- workspace layout ----
    char* wp = (char*)d_ws;
    uint4* Pr  = (uint4*)wp;  wp += (size_t)NG_TOT * G_DIM * 16;   // 512 KB
    uint4* Pn  = (uint4*)wp;  wp += (size_t)NG_TOT * G_DIM * 16;   // 512 KB
    uint4* PWr = (uint4*)wp;  wp += (size_t)NG_TOT * G_DIM * 16;   // 512 KB
    uint4* PWn = (uint4*)wp;  wp += (size_t)NG_TOT * G_DIM * 16;   // 512 KB
    float* hsAll = (float*)wp;      wp += (size_t)3 * BHID * 4;    // 196 KB
    float* csAll = (float*)wp;      wp += (size_t)3 * BHID * 4;    // 196 KB
    float* partials = (float*)wp;   wp += (size_t)B_DIM * NPART * 4 * 4;   // 8 KB
    wp = (char*)(((uintptr_t)wp + 255) & ~(uintptr_t)255);
    __half* xzAll = (__half*)wp; wp += (size_t)3 * B_DIM * TC * G_DIM * 2; // 12.6 MB
    __half* h0 = (__half*)wp;    wp += (size_t)B_DIM * T_DIM * U_DIM * 2;  // 16.8 MB
    __half* h1 = (__half*)wp;    wp += (size_t)B_DIM * T_DIM * U_DIM * 2;  // 16.8 MB
    __half* xh = (__half*)wp;    wp += (size_t)B_DIM * T_DIM * U_DIM * 2;  // 16.8 MB
    // total ~66 MB

    // ---- one-time packs ----
    pack_w<<<128, 256, 0, stream>>>(Ur, Pr);
    pack_w<<<128, 256, 0, stream>>>(Un, Pn);
    pack_w<<<128, 256, 0, stream>>>(Wr, PWr);
    pack_w<<<128, 256, 0, stream>>>(Wn, PWn);
    pack_x<<<(B_DIM * T_DIM * U_DIM) / (256 * 8), 256, 0, stream>>>(x, xh);

    // ---- fused wavefront: 18 stream-ordered dispatches, no atomics ----
    for (int slot = 0; slot < NSLOT; ++slot) {
        lstm_slot<<<3 * B_DIM, 512, 0, stream>>>(slot, xh, Pr, Pn, PWr, PWn,
                                                 br, bn, h0, h1, xzAll,
                                                 hsAll, csAll);
    }

    // ---- final projection ----
    final_partial<<<dim3(B_DIM, NPART), 256, 0, stream>>>(h1, hsAll + 2 * BHID,
                                                          Wd, partials);
    final_reduce<<<1, 256, 0, stream>>>(partials, bd, y);
}